// Round 21
// baseline (680.606 us; speedup 1.0000x reference)
//
#include <hip/hip_runtime.h>
#include <stdint.h>

#define NVOX   98280
#define S_SETS 2730
#define L_SET  36
#define D_MODEL 192
#define D_FF    384
#define N_HEADS 8
#define H_DIM   24
#define CFP    200
#define HCP    232   // Hc row stride bytes: 58 dwords == 26 mod 32 -> reads 16-bank, stores 2-way

using s16x8 = __attribute__((ext_vector_type(8))) short;
using s16x4 = __attribute__((ext_vector_type(4))) short;
using f32x4 = __attribute__((ext_vector_type(4))) float;

__device__ __forceinline__ float bf2f(unsigned short h) {
    unsigned u = ((unsigned)h) << 16;
    return __builtin_bit_cast(float, u);
}
__device__ __forceinline__ unsigned short f2bf(float f) {
    unsigned u = __builtin_bit_cast(unsigned, f);
    u += 0x7FFF + ((u >> 16) & 1);
    return (unsigned short)(u >> 16);
}

__global__ __launch_bounds__(256)
void convert_f32_bf16(const float* __restrict__ src, short* __restrict__ dst, int n)
{
    int i = blockIdx.x * 256 + threadIdx.x;
    if (i < n) dst[i] = (short)f2bf(src[i]);
}

// ---------------------------------------------------------------------------
// Gather: qk[f]=bf16(x[v]+pos[v]); sf[f]=bf16(x[v]); v=inds[f].
// ---------------------------------------------------------------------------
__global__ __launch_bounds__(256)
void gather_kernel(const float* __restrict__ x, const float* __restrict__ pos,
                   const int* __restrict__ inds,
                   short* __restrict__ qk, short* __restrict__ sf)
{
    int f = blockIdx.x * 4 + (threadIdx.x >> 6);
    int lane = threadIdx.x & 63;
    if (lane >= 48) return;
    int v = inds[f];
    float4 a = *(const float4*)(x + (size_t)v * D_MODEL + lane * 4);
    float4 p = *(const float4*)(pos + (size_t)v * D_MODEL + lane * 4);
    s16x4 q, s;
    q[0] = (short)f2bf(a.x + p.x); q[1] = (short)f2bf(a.y + p.y);
    q[2] = (short)f2bf(a.z + p.z); q[3] = (short)f2bf(a.w + p.w);
    s[0] = (short)f2bf(a.x); s[1] = (short)f2bf(a.y);
    s[2] = (short)f2bf(a.z); s[3] = (short)f2bf(a.w);
    *(s16x4*)(qk + (size_t)f * D_MODEL + lane * 4) = q;
    *(s16x4*)(sf + (size_t)f * D_MODEL + lane * 4) = s;
}

// ---------------------------------------------------------------------------
// QKV GEMM, A-direct (round-6 winner, unchanged).
// ---------------------------------------------------------------------------
__global__ __launch_bounds__(512, 4)
void qkv_direct(const short* __restrict__ qk, const short* __restrict__ sf,
                const short* __restrict__ W, const float* __restrict__ bias,
                short* __restrict__ C, int n)
{
    __shared__ char Bs[36864];
    const int bx = blockIdx.x;                 // 0..5
    const int sec = bx >> 1, half = bx & 1;
    const int colOff = sec * 192 + half * 96;
    const short* Ap = (sec == 2) ? sf : qk;
    const short* Wp = W + (size_t)colOff * 192;
    const int rowBase = blockIdx.y * 128;
    const int tid = threadIdx.x;

    #pragma unroll
    for (int t = tid; t < 2304; t += 512) {
        int row = t / 24, c8 = t % 24;
        s16x8 v = *(const s16x8*)(Wp + (size_t)row * 192 + c8 * 8);
        *(s16x8*)(Bs + row * 384 + ((c8 * 16) ^ ((row & 7) << 4))) = v;
    }
    __syncthreads();

    const int wid = tid >> 6, lane = tid & 63;
    const int lr = lane & 15, kb = lane >> 4;
    const int arow = rowBase + wid * 16 + lr;
    const bool rv = arow < n;
    const short* Arow = Ap + (size_t)arow * 192 + kb * 8;

    f32x4 acc[6] = {};
    #pragma unroll
    for (int ks = 0; ks < 6; ++ks) {
        s16x8 a = {};
        if (rv) a = *(const s16x8*)(Arow + ks * 32);
        s16x8 b[6];
        #pragma unroll
        for (int fj = 0; fj < 6; ++fj) {
            int row = fj * 16 + lr;
            b[fj] = *(const s16x8*)(Bs + row * 384 + ((ks * 64 + kb * 16) ^ ((row & 7) << 4)));
        }
        #pragma unroll
        for (int fj = 0; fj < 6; ++fj)
            acc[fj] = __builtin_amdgcn_mfma_f32_16x16x32_bf16(a, b[fj], acc[fj], 0, 0, 0);
    }
    #pragma unroll
    for (int fj = 0; fj < 6; ++fj) {
        int col = colOff + fj * 16 + lr;
        float bv = bias[col];
        #pragma unroll
        for (int r = 0; r < 4; ++r) {
            int grow = rowBase + wid * 16 + kb * 4 + r;
            if (grow < n)
                C[(size_t)grow * 576 + col] = (short)f2bf(acc[fj][r] + bv);
        }
    }
}

// ---------------------------------------------------------------------------
// MFMA attention v3 (round-15 winner: 4 waves/block, unchanged).
// ---------------------------------------------------------------------------
__global__ __launch_bounds__(256)
void attn_mfma(const short* __restrict__ qkv, const unsigned char* __restrict__ mask,
               short* __restrict__ attn_out)
{
    __shared__ short Plall[4 * 48 * 64];
    const int wid = threadIdx.x >> 6;
    const int lane = threadIdx.x & 63;
    const int p = blockIdx.x * 4 + wid;
    const int s = p >> 3;
    const int h = p & 7;
    short* Pl = Plall + wid * 48 * 64;
    char* Pb = (char*)Pl;
    const int lr = lane & 15, g = lane >> 4;

    #pragma unroll
    for (int i = 0; i < 6; ++i)
        *(s16x8*)(Pl + i * 512 + lane * 8) = (s16x8){};

    s16x8 qa[3], kb3[3];
    #pragma unroll
    for (int t = 0; t < 3; ++t) {
        int rr = t * 16 + lr;
        qa[t] = (s16x8){};
        kb3[t] = (s16x8){};
        if (rr < L_SET && g < 3) {
            const short* base = qkv + (size_t)(s * L_SET + rr) * 576 + h * H_DIM + g * 8;
            qa[t] = *(const s16x8*)(base);
            kb3[t] = *(const s16x8*)(base + 192);
        }
    }
    f32x4 sc[3][3] = {};
    #pragma unroll
    for (int mt = 0; mt < 3; ++mt)
        #pragma unroll
        for (int nt = 0; nt < 3; ++nt)
            sc[mt][nt] = __builtin_amdgcn_mfma_f32_16x16x32_bf16(qa[mt], kb3[nt], sc[mt][nt], 0, 0, 0);

    s16x8 vb[2][2];
    #pragma unroll
    for (int ks = 0; ks < 2; ++ks)
        #pragma unroll
        for (int nt = 0; nt < 2; ++nt)
            #pragma unroll
            for (int e = 0; e < 8; ++e) {
                size_t row = (size_t)s * L_SET + ks * 32 + g * 8 + e;
                vb[ks][nt][e] = qkv[row * 576 + 384 + h * H_DIM + nt * 16 + lr];
            }

    const float scale = 0.20412414523193154f;      // 1/sqrt(24)
    bool colmask[3];
    #pragma unroll
    for (int nt = 0; nt < 3; ++nt) {
        int m = nt * 16 + lr;
        colmask[nt] = (m >= L_SET) || (mask[(size_t)s * L_SET + (m < L_SET ? m : 0)] != 0);
    }
    #pragma unroll
    for (int mt = 0; mt < 3; ++mt) {
        #pragma unroll
        for (int r = 0; r < 4; ++r) {
            float v[3], ev[3];
            #pragma unroll
            for (int nt = 0; nt < 3; ++nt)
                v[nt] = colmask[nt] ? -1e9f : sc[mt][nt][r] * scale;
            float mx = fmaxf(fmaxf(v[0], v[1]), v[2]);
            #pragma unroll
            for (int off = 1; off < 16; off <<= 1) mx = fmaxf(mx, __shfl_xor(mx, off, 64));
            float sm = 0.f;
            #pragma unroll
            for (int nt = 0; nt < 3; ++nt) { ev[nt] = __expf(v[nt] - mx); sm += ev[nt]; }
            #pragma unroll
            for (int off = 1; off < 16; off <<= 1) sm += __shfl_xor(sm, off, 64);
            float rinv = 1.f / sm;
            int q = mt * 16 + g * 4 + r;
            #pragma unroll
            for (int nt = 0; nt < 3; ++nt) {
                int m = nt * 16 + lr;
                *(short*)(Pb + q * 128 + ((m * 2) ^ ((q & 7) << 4))) =
                    (short)f2bf(ev[nt] * rinv);
            }
        }
    }

    f32x4 o[3][2] = {};
    #pragma unroll
    for (int ks = 0; ks < 2; ++ks) {
        s16x8 pa[3];
        #pragma unroll
        for (int mt = 0; mt < 3; ++mt) {
            int row = mt * 16 + lr;
            pa[mt] = *(const s16x8*)(Pb + row * 128 + ((ks * 64 + g * 16) ^ ((row & 7) << 4)));
        }
        #pragma unroll
        for (int mt = 0; mt < 3; ++mt)
            #pragma unroll
            for (int nt = 0; nt < 2; ++nt)
                o[mt][nt] = __builtin_amdgcn_mfma_f32_16x16x32_bf16(pa[mt], vb[ks][nt], o[mt][nt], 0, 0, 0);
    }

    #pragma unroll
    for (int mt = 0; mt < 3; ++mt) {
        #pragma unroll
        for (int nt = 0; nt < 2; ++nt) {
            #pragma unroll
            for (int r = 0; r < 4; ++r) {
                int q = mt * 16 + g * 4 + r;
                int d = nt * 16 + lr;
                if (q < L_SET && d < H_DIM)
                    attn_out[(size_t)(s * L_SET + q) * D_MODEL + h * H_DIM + d] =
                        (short)f2bf(o[mt][nt][r]);
            }
        }
    }
}

__device__ __forceinline__ float wave_sum64(float v) {
    #pragma unroll
    for (int off = 32; off > 0; off >>= 1) v += __shfl_xor(v, off, 64);
    return v;
}

// ---------------------------------------------------------------------------
// Wo GEMM + LN1 fused, 1024 threads (round-20 winner, unchanged).
// ---------------------------------------------------------------------------
__global__ __launch_bounds__(1024)
void wo_ln1(const short* __restrict__ attnb, const short* __restrict__ Wo,
            const float* __restrict__ bo, const int* __restrict__ inds,
            const float* __restrict__ xin,
            const float* __restrict__ g1, const float* __restrict__ be1,
            short* __restrict__ x1, int n)
{
    extern __shared__ char pool[];
    char* As = pool;
    char* Bs = pool + 49152;
    float* Cf = (float*)pool;
    const int rowBase = blockIdx.x * 128;
    const int tid = threadIdx.x;
    const int wid = tid >> 6, lane = tid & 63;
    const int lr = lane & 15, kb = lane >> 4;
    const int wm = wid & 7;                 // 16-row group
    const int wn = wid >> 3;                // 96-col group

    int vv[8];
    #pragma unroll
    for (int i = 0; i < 8; ++i) {
        int f = rowBase + wid * 8 + i;
        vv[i] = (f < n) ? inds[f] : 0;
    }
    float4 gv = (lane < 48) ? *(const float4*)(g1 + lane * 4) : make_float4(0,0,0,0);
    float4 bv = (lane < 48) ? *(const float4*)(be1 + lane * 4) : make_float4(0,0,0,0);

    #pragma unroll
    for (int t = tid; t < 3072; t += 1024) {
        int row = t / 24, c8 = t % 24;
        int grow = rowBase + row;
        s16x8 v = {};
        if (grow < n) v = *(const s16x8*)(attnb + (size_t)grow * 192 + c8 * 8);
        *(s16x8*)(As + row * 384 + ((c8 * 16) ^ ((row & 7) << 4))) = v;
    }
    #pragma unroll
    for (int t = tid; t < 4608; t += 1024) {
        int row = t / 24, c8 = t % 24;
        s16x8 v = *(const s16x8*)(Wo + (size_t)row * 192 + c8 * 8);
        *(s16x8*)(Bs + row * 384 + ((c8 * 16) ^ ((row & 7) << 4))) = v;
    }
    __syncthreads();

    float4 xr[8];
    #pragma unroll
    for (int i = 0; i < 8; ++i)
        xr[i] = (lane < 48) ? *(const float4*)(xin + (size_t)vv[i] * D_MODEL + lane * 4)
                            : make_float4(0.f, 0.f, 0.f, 0.f);

    f32x4 acc[6] = {};
    #pragma unroll
    for (int ks = 0; ks < 6; ++ks) {
        int row = wm * 16 + lr;
        s16x8 a = *(const s16x8*)(As + row * 384 + ((ks * 64 + kb * 16) ^ ((row & 7) << 4)));
        s16x8 b[6];
        #pragma unroll
        for (int fj = 0; fj < 6; ++fj) {
            int brow = wn * 96 + fj * 16 + lr;
            b[fj] = *(const s16x8*)(Bs + brow * 384 + ((ks * 64 + kb * 16) ^ ((brow & 7) << 4)));
        }
        #pragma unroll
        for (int fj = 0; fj < 6; ++fj)
            acc[fj] = __builtin_amdgcn_mfma_f32_16x16x32_bf16(a, b[fj], acc[fj], 0, 0, 0);
    }
    __syncthreads();
    #pragma unroll
    for (int fj = 0; fj < 6; ++fj) {
        int col = wn * 96 + fj * 16 + lr;
        float bvv = bo[col];
        #pragma unroll
        for (int r = 0; r < 4; ++r) {
            int row = wm * 16 + kb * 4 + r;
            Cf[row * CFP + col] = acc[fj][r] + bvv;
        }
    }
    __syncthreads();

    #pragma unroll
    for (int i = 0; i < 8; ++i) {
        int r = wid * 8 + i;
        int f = rowBase + r;
        float4 t = make_float4(0.f, 0.f, 0.f, 0.f);
        if (lane < 48) {
            float4 c4 = *(const float4*)&Cf[r * CFP + lane * 4];
            t.x = c4.x + xr[i].x; t.y = c4.y + xr[i].y;
            t.z = c4.z + xr[i].z; t.w = c4.w + xr[i].w;
        }
        float mean = wave_sum64(t.x + t.y + t.z + t.w) * (1.f / 192.f);
        float ss   = wave_sum64(t.x*t.x + t.y*t.y + t.z*t.z + t.w*t.w) * (1.f / 192.f);
        float inv = rsqrtf(ss - mean * mean + 1e-5f);
        if (lane < 48 && f < n) {
            s16x4 o;
            o[0] = (short)f2bf((t.x - mean) * inv * gv.x + bv.x);
            o[1] = (short)f2bf((t.y - mean) * inv * gv.y + bv.y);
            o[2] = (short)f2bf((t.z - mean) * inv * gv.z + bv.z);
            o[3] = (short)f2bf((t.w - mean) * inv * gv.w + bv.w);
            *(s16x4*)(x1 + (size_t)vv[i] * D_MODEL + lane * 4) = o;
        }
    }
}

// ---------------------------------------------------------------------------
// FFN fused, 1024 threads (r19 winner) + Hc stride 208 -> HCP=232 to break
// the 4-way store / 8-bank read conflicts (the 5.0M SQ_LDS_BANK_CONFLICT).
// LDS = 125952 + 128*232 = 155648 < 160K.
// ---------------------------------------------------------------------------
__global__ __launch_bounds__(1024)
void ffn_fused(const short* __restrict__ x1, const short* __restrict__ W1,
               const float* __restrict__ b1, const short* __restrict__ W2,
               const float* __restrict__ b2, const float* __restrict__ xin,
               const float* __restrict__ g2, const float* __restrict__ be2,
               const float* __restrict__ gn, const float* __restrict__ bn,
               float* __restrict__ outp, int n)
{
    extern __shared__ char pool[];
    char* Ax  = pool;
    char* W1c = pool + 49152;
    char* W2c = pool + 86016;
    char* Hc  = pool + 125952;              // 128 * HCP = 29696
    float* Cf = (float*)(pool + 49152);
    const int rowBase = blockIdx.x * 128;
    const int tid = threadIdx.x;
    const int wid = tid >> 6, lane = tid & 63;
    const int lr = lane & 15, kb = lane >> 4;
    const int wm = wid & 7;
    const int wn = wid >> 3;

    s16x8 w1r[3], w2r[3];
    #pragma unroll
    for (int i = 0; i < 3; ++i) {
        int t = i * 1024 + tid;
        w1r[i] = (s16x8){}; w2r[i] = (s16x8){};
        if (t < 2304) {
            int row = t / 24, c8 = t % 24;
            w1r[i] = *(const s16x8*)(W1 + (size_t)row * 192 + c8 * 8);
            int row2 = t / 12, c82 = t % 12;
            w2r[i] = *(const s16x8*)(W2 + (size_t)row2 * 384 + c82 * 8);
        }
    }

    #pragma unroll
    for (int t = tid; t < 3072; t += 1024) {
        int row = t / 24, c8 = t % 24;
        int grow = rowBase + row;
        s16x8 v = {};
        if (grow < n) v = *(const s16x8*)(x1 + (size_t)grow * 192 + c8 * 8);
        *(s16x8*)(Ax + row * 384 + ((c8 * 16) ^ ((row & 7) << 4))) = v;
    }

    f32x4 acc2[6] = {};
    for (int c = 0; c < 4; ++c) {
        __syncthreads();
        #pragma unroll
        for (int i = 0; i < 3; ++i) {
            int t = i * 1024 + tid;
            if (t < 2304) {
                int row = t / 24, c8 = t % 24;
                *(s16x8*)(W1c + row * 384 + ((c8 * 16) ^ ((row & 7) << 4))) = w1r[i];
                int row2 = t / 12, c82 = t % 12;
                *(s16x8*)(W2c + row2 * 208 + c82 * 16) = w2r[i];
            }
        }
        __syncthreads();
        if (c < 3) {
            #pragma unroll
            for (int i = 0; i < 3; ++i) {
                int t = i * 1024 + tid;
                if (t < 2304) {
                    int row = t / 24, c8 = t % 24;
                    w1r[i] = *(const s16x8*)(W1 + (size_t)((c + 1) * 96 + row) * 192 + c8 * 8);
                    int row2 = t / 12, c82 = t % 12;
                    w2r[i] = *(const s16x8*)(W2 + (size_t)row2 * 384 + (c + 1) * 96 + c82 * 8);
                }
            }
        }
        f32x4 acc1[3] = {};
        #pragma unroll
        for (int ks = 0; ks < 6; ++ks) {
            int row = wm * 16 + lr;
            s16x8 a = *(const s16x8*)(Ax + row * 384 + ((ks * 64 + kb * 16) ^ ((row & 7) << 4)));
            s16x8 b[3];
            #pragma unroll
            for (int fj = 0; fj < 3; ++fj) {
                int brow = wn * 48 + fj * 16 + lr;
                b[fj] = *(const s16x8*)(W1c + brow * 384 + ((ks * 64 + kb * 16) ^ ((brow & 7) << 4)));
            }
            #pragma unroll
            for (int fj = 0; fj < 3; ++fj)
                acc1[fj] = __builtin_amdgcn_mfma_f32_16x16x32_bf16(a, b[fj], acc1[fj], 0, 0, 0);
        }
        #pragma unroll
        for (int fj = 0; fj < 3; ++fj) {
            int col = wn * 48 + fj * 16 + lr;
            float b1v = b1[c * 96 + col];
            #pragma unroll
            for (int r = 0; r < 4; ++r) {
                int row = wm * 16 + kb * 4 + r;
                *(short*)(Hc + row * HCP + col * 2) =
                    (short)f2bf(fmaxf(acc1[fj][r] + b1v, 0.f));
            }
        }
        __syncthreads();
        #pragma unroll
        for (int ks = 0; ks < 3; ++ks) {
            int row = wm * 16 + lr;
            s16x8 a = *(const s16x8*)(Hc + row * HCP + ks * 64 + kb * 16);
            s16x8 b[6];
            #pragma unroll
            for (int fj = 0; fj < 6; ++fj) {
                int brow = wn * 96 + fj * 16 + lr;
                b[fj] = *(const s16x8*)(W2c + brow * 208 + ks * 64 + kb * 16);
            }
            #pragma unroll
            for (int fj = 0; fj < 6; ++fj)
                acc2[fj] = __builtin_amdgcn_mfma_f32_16x16x32_bf16(a, b[fj], acc2[fj], 0, 0, 0);
        }
    }

    float4 xr[8];
    #pragma unroll
    for (int i = 0; i < 8; ++i) {
        int gvx = rowBase + wid * 8 + i;
        xr[i] = (lane < 48 && gvx < n)
              ? *(const float4*)(xin + (size_t)gvx * D_MODEL + lane * 4)
              : make_float4(0.f, 0.f, 0.f, 0.f);
    }
    float4 g2v = (lane < 48) ? *(const float4*)(g2 + lane * 4) : make_float4(0,0,0,0);
    float4 b2v = (lane < 48) ? *(const float4*)(be2 + lane * 4) : make_float4(0,0,0,0);
    float4 gnv = (lane < 48) ? *(const float4*)(gn + lane * 4) : make_float4(0,0,0,0);
    float4 bnv = (lane < 48) ? *(const float4*)(bn + lane * 4) : make_float4(0,0,0,0);

    __syncthreads();
    #pragma unroll
    for (int fj = 0; fj < 6; ++fj) {
        int col = wn * 96 + fj * 16 + lr;
        float bvv = b2[col];
        #pragma unroll
        for (int r = 0; r < 4; ++r) {
            int row = wm * 16 + kb * 4 + r;
            Cf[row * CFP + col] = acc2[fj][r] + bvv;
        }
    }
    __syncthreads();

    #pragma unroll
    for (int i = 0; i < 8; ++i) {
        int r = wid * 8 + i;
        int gvx = rowBase + r;
        float4 t = make_float4(0.f, 0.f, 0.f, 0.f);
        if (lane < 48) {
            float4 f4 = *(const float4*)&Cf[r * CFP + lane * 4];
            int byteoff = r * 384 + (((lane >> 1) << 4) ^ ((r & 7) << 4)) + ((lane & 1) << 3);
            s16x4 xv = *(const s16x4*)(Ax + byteoff);
            t.x = f4.x + bf2f((unsigned short)xv[0]);
            t.y = f4.y + bf2f((unsigned short)xv[1]);
            t.z = f4.z + bf2f((unsigned short)xv[2]);
            t.w = f4.w + bf2f((unsigned short)xv[3]);
        }
        float m1 = wave_sum64(t.x + t.y + t.z + t.w) * (1.f / 192.f);
        float s1 = wave_sum64(t.x*t.x + t.y*t.y + t.z*t.z + t.w*t.w) * (1.f / 192.f);
        float i1 = rsqrtf(s1 - m1 * m1 + 1e-5f);
        float4 t2 = make_float4(0.f, 0.f, 0.f, 0.f);
        if (lane < 48) {
            t2.x = (t.x - m1) * i1 * g2v.x + b2v.x + xr[i].x;
            t2.y = (t.y - m1) * i1 * g2v.y + b2v.y + xr[i].y;
            t2.z = (t.z - m1) * i1 * g2v.z + b2v.z + xr[i].z;
            t2.w = (t.w - m1) * i1 * g2v.w + b2v.w + xr[i].w;
        }
        float m2 = wave_sum64(t2.x + t2.y + t2.z + t2.w) * (1.f / 192.f);
        float s2 = wave_sum64(t2.x*t2.x + t2.y*t2.y + t2.z*t2.z + t2.w*t2.w) * (1.f / 192.f);
        float i2 = rsqrtf(s2 - m2 * m2 + 1e-5f);
        if (lane < 48 && gvx < n) {
            float4 o;
            o.x = (t2.x - m2) * i2 * gnv.x + bnv.x;
            o.y = (t2.y - m2) * i2 * gnv.y + bnv.y;
            o.z = (t2.z - m2) * i2 * gnv.z + bnv.z;
            o.w = (t2.w - m2) * i2 * gnv.w + bnv.w;
            *(float4*)(outp + (size_t)gvx * D_MODEL + lane * 4) = o;
        }
    }
}

// ---------------------------------------------------------------------------
extern "C" void kernel_launch(void* const* d_in, const int* in_sizes, int n_in,
                              void* d_out, int out_size, void* d_ws, size_t ws_size,
                              hipStream_t stream)
{
    (void)in_sizes; (void)n_in; (void)out_size;
    const int N = NVOX;
    const float* src = (const float*)d_in[0];
    const int* inds[2] = {(const int*)d_in[1], (const int*)d_in[2]};
    const unsigned char* mask[2] = {(const unsigned char*)d_in[3], (const unsigned char*)d_in[4]};
    const float* pos[2] = {(const float*)d_in[5], (const float*)d_in[6]};
    const float* Wqkv = (const float*)d_in[7];
    const float* bqkv = (const float*)d_in[8];
    const float* Wo   = (const float*)d_in[9];
    const float* bo   = (const float*)d_in[10];
    const float* W1   = (const float*)d_in[11];
    const float* b1   = (const float*)d_in[12];
    const float* W2   = (const float*)d_in[13];
    const float* b2   = (const float*)d_in[14];
    const float* g1   = (const float*)d_in[15];
    const float* be1  = (const float*)d_in[16];
    const float* g2   = (const float*)d_in[17];
    const float* be2  = (const float*)d_in[18];
    const float* gn   = (const float*)d_in[19];
    const float* bn   = (const float*)d_in[20];

    float* out = (float*)d_out;
    short* wsS = (short*)d_ws;

    const size_t NE = (size_t)N * D_MODEL;
    short* wqkv_b = wsS;
    short* wo_b   = wsS + 221184;
    short* w1_b   = wsS + 294912;
    short* w2_b   = wsS + 442368;
    const size_t base = 1048576;
    short* qk    = wsS + base;
    short* sf    = qk + NE;
    short* qkvb  = sf + NE;
    short* attnb = qkvb + 3 * NE;
    short* x1    = attnb + NE;

    if (ws_size < (base + 7 * NE) * sizeof(short)) return;

    const dim3 blk(256);
    convert_f32_bf16<<<dim3(864), blk, 0, stream>>>(Wqkv, wqkv_b, 221184);
    convert_f32_bf16<<<dim3(288), blk, 0, stream>>>(Wo,   wo_b,   73728);
    convert_f32_bf16<<<dim3(576), blk, 0, stream>>>(W1,   w1_b,   147456);
    convert_f32_bf16<<<dim3(576), blk, 0, stream>>>(W2,   w2_b,   147456);

    const int RT = (N + 127) / 128;                  // 768 row tiles
    for (int i = 0; i < 2; ++i) {
        const float* xin = (i == 0) ? src : out;
        gather_kernel<<<dim3(24570), blk, 0, stream>>>(xin, pos[i], inds[i], qk, sf);
        qkv_direct<<<dim3(6, RT), dim3(512), 0, stream>>>(
            qk, sf, wqkv_b + (size_t)i * 110592, bqkv + i * 576, qkvb, N);
        attn_mfma<<<dim3(S_SETS * N_HEADS / 4), dim3(256), 0, stream>>>(qkvb, mask[i], attnb);
        wo_ln1<<<dim3(RT), dim3(1024), 122880, stream>>>(
            attnb, wo_b + (size_t)i * 36864, bo + i * 192, inds[i], xin,
            g1 + i * 192, be1 + i * 192, x1, N);
        ffn_fused<<<dim3(RT), dim3(1024), 155648, stream>>>(
            x1, w1_b + (size_t)i * 73728, b1 + i * 384, w2_b + (size_t)i * 73728,
            b2 + i * 192, xin, g2 + i * 192, be2 + i * 192,
            gn + i * 192, bn + i * 192, out, N);
    }
}

// Round 22
// 652.726 us; speedup vs baseline: 1.0427x; 1.0427x over previous
//
#include <hip/hip_runtime.h>
#include <stdint.h>

#define NVOX   98280
#define S_SETS 2730
#define L_SET  36
#define D_MODEL 192
#define D_FF    384
#define N_HEADS 8
#define H_DIM   24
#define CFP    200

using s16x8 = __attribute__((ext_vector_type(8))) short;
using s16x4 = __attribute__((ext_vector_type(4))) short;
using f32x4 = __attribute__((ext_vector_type(4))) float;

__device__ __forceinline__ float bf2f(unsigned short h) {
    unsigned u = ((unsigned)h) << 16;
    return __builtin_bit_cast(float, u);
}
__device__ __forceinline__ unsigned short f2bf(float f) {
    unsigned u = __builtin_bit_cast(unsigned, f);
    u += 0x7FFF + ((u >> 16) & 1);
    return (unsigned short)(u >> 16);
}

__global__ __launch_bounds__(256)
void convert_f32_bf16(const float* __restrict__ src, short* __restrict__ dst, int n)
{
    int i = blockIdx.x * 256 + threadIdx.x;
    if (i < n) dst[i] = (short)f2bf(src[i]);
}

// ---------------------------------------------------------------------------
// Gather: qk[f]=bf16(x[v]+pos[v]); sf[f]=bf16(x[v]); v=inds[f].
// (r18 proved fusing this into qkv re-reads the random f32 rows 6x; keep it.)
// ---------------------------------------------------------------------------
__global__ __launch_bounds__(256)
void gather_kernel(const float* __restrict__ x, const float* __restrict__ pos,
                   const int* __restrict__ inds,
                   short* __restrict__ qk, short* __restrict__ sf)
{
    int f = blockIdx.x * 4 + (threadIdx.x >> 6);
    int lane = threadIdx.x & 63;
    if (lane >= 48) return;
    int v = inds[f];
    float4 a = *(const float4*)(x + (size_t)v * D_MODEL + lane * 4);
    float4 p = *(const float4*)(pos + (size_t)v * D_MODEL + lane * 4);
    s16x4 q, s;
    q[0] = (short)f2bf(a.x + p.x); q[1] = (short)f2bf(a.y + p.y);
    q[2] = (short)f2bf(a.z + p.z); q[3] = (short)f2bf(a.w + p.w);
    s[0] = (short)f2bf(a.x); s[1] = (short)f2bf(a.y);
    s[2] = (short)f2bf(a.z); s[3] = (short)f2bf(a.w);
    *(s16x4*)(qk + (size_t)f * D_MODEL + lane * 4) = q;
    *(s16x4*)(sf + (size_t)f * D_MODEL + lane * 4) = s;
}

// ---------------------------------------------------------------------------
// QKV GEMM, A-direct (round-6 winner).
// ---------------------------------------------------------------------------
__global__ __launch_bounds__(512, 4)
void qkv_direct(const short* __restrict__ qk, const short* __restrict__ sf,
                const short* __restrict__ W, const float* __restrict__ bias,
                short* __restrict__ C, int n)
{
    __shared__ char Bs[36864];
    const int bx = blockIdx.x;                 // 0..5
    const int sec = bx >> 1, half = bx & 1;
    const int colOff = sec * 192 + half * 96;
    const short* Ap = (sec == 2) ? sf : qk;
    const short* Wp = W + (size_t)colOff * 192;
    const int rowBase = blockIdx.y * 128;
    const int tid = threadIdx.x;

    #pragma unroll
    for (int t = tid; t < 2304; t += 512) {
        int row = t / 24, c8 = t % 24;
        s16x8 v = *(const s16x8*)(Wp + (size_t)row * 192 + c8 * 8);
        *(s16x8*)(Bs + row * 384 + ((c8 * 16) ^ ((row & 7) << 4))) = v;
    }
    __syncthreads();

    const int wid = tid >> 6, lane = tid & 63;
    const int lr = lane & 15, kb = lane >> 4;
    const int arow = rowBase + wid * 16 + lr;
    const bool rv = arow < n;
    const short* Arow = Ap + (size_t)arow * 192 + kb * 8;

    f32x4 acc[6] = {};
    #pragma unroll
    for (int ks = 0; ks < 6; ++ks) {
        s16x8 a = {};
        if (rv) a = *(const s16x8*)(Arow + ks * 32);
        s16x8 b[6];
        #pragma unroll
        for (int fj = 0; fj < 6; ++fj) {
            int row = fj * 16 + lr;
            b[fj] = *(const s16x8*)(Bs + row * 384 + ((ks * 64 + kb * 16) ^ ((row & 7) << 4)));
        }
        #pragma unroll
        for (int fj = 0; fj < 6; ++fj)
            acc[fj] = __builtin_amdgcn_mfma_f32_16x16x32_bf16(a, b[fj], acc[fj], 0, 0, 0);
    }
    #pragma unroll
    for (int fj = 0; fj < 6; ++fj) {
        int col = colOff + fj * 16 + lr;
        float bv = bias[col];
        #pragma unroll
        for (int r = 0; r < 4; ++r) {
            int grow = rowBase + wid * 16 + kb * 4 + r;
            if (grow < n)
                C[(size_t)grow * 576 + col] = (short)f2bf(acc[fj][r] + bv);
        }
    }
}

// ---------------------------------------------------------------------------
// MFMA attention v3 (round-15 winner: 4 waves/block).
// ---------------------------------------------------------------------------
__global__ __launch_bounds__(256)
void attn_mfma(const short* __restrict__ qkv, const unsigned char* __restrict__ mask,
               short* __restrict__ attn_out)
{
    __shared__ short Plall[4 * 48 * 64];
    const int wid = threadIdx.x >> 6;
    const int lane = threadIdx.x & 63;
    const int p = blockIdx.x * 4 + wid;
    const int s = p >> 3;
    const int h = p & 7;
    short* Pl = Plall + wid * 48 * 64;
    char* Pb = (char*)Pl;
    const int lr = lane & 15, g = lane >> 4;

    #pragma unroll
    for (int i = 0; i < 6; ++i)
        *(s16x8*)(Pl + i * 512 + lane * 8) = (s16x8){};

    s16x8 qa[3], kb3[3];
    #pragma unroll
    for (int t = 0; t < 3; ++t) {
        int rr = t * 16 + lr;
        qa[t] = (s16x8){};
        kb3[t] = (s16x8){};
        if (rr < L_SET && g < 3) {
            const short* base = qkv + (size_t)(s * L_SET + rr) * 576 + h * H_DIM + g * 8;
            qa[t] = *(const s16x8*)(base);
            kb3[t] = *(const s16x8*)(base + 192);
        }
    }
    f32x4 sc[3][3] = {};
    #pragma unroll
    for (int mt = 0; mt < 3; ++mt)
        #pragma unroll
        for (int nt = 0; nt < 3; ++nt)
            sc[mt][nt] = __builtin_amdgcn_mfma_f32_16x16x32_bf16(qa[mt], kb3[nt], sc[mt][nt], 0, 0, 0);

    s16x8 vb[2][2];
    #pragma unroll
    for (int ks = 0; ks < 2; ++ks)
        #pragma unroll
        for (int nt = 0; nt < 2; ++nt)
            #pragma unroll
            for (int e = 0; e < 8; ++e) {
                size_t row = (size_t)s * L_SET + ks * 32 + g * 8 + e;
                vb[ks][nt][e] = qkv[row * 576 + 384 + h * H_DIM + nt * 16 + lr];
            }

    const float scale = 0.20412414523193154f;      // 1/sqrt(24)
    bool colmask[3];
    #pragma unroll
    for (int nt = 0; nt < 3; ++nt) {
        int m = nt * 16 + lr;
        colmask[nt] = (m >= L_SET) || (mask[(size_t)s * L_SET + (m < L_SET ? m : 0)] != 0);
    }
    #pragma unroll
    for (int mt = 0; mt < 3; ++mt) {
        #pragma unroll
        for (int r = 0; r < 4; ++r) {
            float v[3], ev[3];
            #pragma unroll
            for (int nt = 0; nt < 3; ++nt)
                v[nt] = colmask[nt] ? -1e9f : sc[mt][nt][r] * scale;
            float mx = fmaxf(fmaxf(v[0], v[1]), v[2]);
            #pragma unroll
            for (int off = 1; off < 16; off <<= 1) mx = fmaxf(mx, __shfl_xor(mx, off, 64));
            float sm = 0.f;
            #pragma unroll
            for (int nt = 0; nt < 3; ++nt) { ev[nt] = __expf(v[nt] - mx); sm += ev[nt]; }
            #pragma unroll
            for (int off = 1; off < 16; off <<= 1) sm += __shfl_xor(sm, off, 64);
            float rinv = 1.f / sm;
            int q = mt * 16 + g * 4 + r;
            #pragma unroll
            for (int nt = 0; nt < 3; ++nt) {
                int m = nt * 16 + lr;
                *(short*)(Pb + q * 128 + ((m * 2) ^ ((q & 7) << 4))) =
                    (short)f2bf(ev[nt] * rinv);
            }
        }
    }

    f32x4 o[3][2] = {};
    #pragma unroll
    for (int ks = 0; ks < 2; ++ks) {
        s16x8 pa[3];
        #pragma unroll
        for (int mt = 0; mt < 3; ++mt) {
            int row = mt * 16 + lr;
            pa[mt] = *(const s16x8*)(Pb + row * 128 + ((ks * 64 + g * 16) ^ ((row & 7) << 4)));
        }
        #pragma unroll
        for (int mt = 0; mt < 3; ++mt)
            #pragma unroll
            for (int nt = 0; nt < 2; ++nt)
                o[mt][nt] = __builtin_amdgcn_mfma_f32_16x16x32_bf16(pa[mt], vb[ks][nt], o[mt][nt], 0, 0, 0);
    }

    #pragma unroll
    for (int mt = 0; mt < 3; ++mt) {
        #pragma unroll
        for (int nt = 0; nt < 2; ++nt) {
            #pragma unroll
            for (int r = 0; r < 4; ++r) {
                int q = mt * 16 + g * 4 + r;
                int d = nt * 16 + lr;
                if (q < L_SET && d < H_DIM)
                    attn_out[(size_t)(s * L_SET + q) * D_MODEL + h * H_DIM + d] =
                        (short)f2bf(o[mt][nt][r]);
            }
        }
    }
}

__device__ __forceinline__ float wave_sum64(float v) {
    #pragma unroll
    for (int off = 32; off > 0; off >>= 1) v += __shfl_xor(v, off, 64);
    return v;
}

// ---------------------------------------------------------------------------
// Wo GEMM + LN1 fused, 1024 threads (round-20 winner).
// ---------------------------------------------------------------------------
__global__ __launch_bounds__(1024)
void wo_ln1(const short* __restrict__ attnb, const short* __restrict__ Wo,
            const float* __restrict__ bo, const int* __restrict__ inds,
            const float* __restrict__ xin,
            const float* __restrict__ g1, const float* __restrict__ be1,
            short* __restrict__ x1, int n)
{
    extern __shared__ char pool[];
    char* As = pool;
    char* Bs = pool + 49152;
    float* Cf = (float*)pool;
    const int rowBase = blockIdx.x * 128;
    const int tid = threadIdx.x;
    const int wid = tid >> 6, lane = tid & 63;
    const int lr = lane & 15, kb = lane >> 4;
    const int wm = wid & 7;                 // 16-row group
    const int wn = wid >> 3;                // 96-col group

    int vv[8];
    #pragma unroll
    for (int i = 0; i < 8; ++i) {
        int f = rowBase + wid * 8 + i;
        vv[i] = (f < n) ? inds[f] : 0;
    }
    float4 gv = (lane < 48) ? *(const float4*)(g1 + lane * 4) : make_float4(0,0,0,0);
    float4 bv = (lane < 48) ? *(const float4*)(be1 + lane * 4) : make_float4(0,0,0,0);

    #pragma unroll
    for (int t = tid; t < 3072; t += 1024) {
        int row = t / 24, c8 = t % 24;
        int grow = rowBase + row;
        s16x8 v = {};
        if (grow < n) v = *(const s16x8*)(attnb + (size_t)grow * 192 + c8 * 8);
        *(s16x8*)(As + row * 384 + ((c8 * 16) ^ ((row & 7) << 4))) = v;
    }
    #pragma unroll
    for (int t = tid; t < 4608; t += 1024) {
        int row = t / 24, c8 = t % 24;
        s16x8 v = *(const s16x8*)(Wo + (size_t)row * 192 + c8 * 8);
        *(s16x8*)(Bs + row * 384 + ((c8 * 16) ^ ((row & 7) << 4))) = v;
    }
    __syncthreads();

    float4 xr[8];
    #pragma unroll
    for (int i = 0; i < 8; ++i)
        xr[i] = (lane < 48) ? *(const float4*)(xin + (size_t)vv[i] * D_MODEL + lane * 4)
                            : make_float4(0.f, 0.f, 0.f, 0.f);

    f32x4 acc[6] = {};
    #pragma unroll
    for (int ks = 0; ks < 6; ++ks) {
        int row = wm * 16 + lr;
        s16x8 a = *(const s16x8*)(As + row * 384 + ((ks * 64 + kb * 16) ^ ((row & 7) << 4)));
        s16x8 b[6];
        #pragma unroll
        for (int fj = 0; fj < 6; ++fj) {
            int brow = wn * 96 + fj * 16 + lr;
            b[fj] = *(const s16x8*)(Bs + brow * 384 + ((ks * 64 + kb * 16) ^ ((brow & 7) << 4)));
        }
        #pragma unroll
        for (int fj = 0; fj < 6; ++fj)
            acc[fj] = __builtin_amdgcn_mfma_f32_16x16x32_bf16(a, b[fj], acc[fj], 0, 0, 0);
    }
    __syncthreads();
    #pragma unroll
    for (int fj = 0; fj < 6; ++fj) {
        int col = wn * 96 + fj * 16 + lr;
        float bvv = bo[col];
        #pragma unroll
        for (int r = 0; r < 4; ++r) {
            int row = wm * 16 + kb * 4 + r;
            Cf[row * CFP + col] = acc[fj][r] + bvv;
        }
    }
    __syncthreads();

    #pragma unroll
    for (int i = 0; i < 8; ++i) {
        int r = wid * 8 + i;
        int f = rowBase + r;
        float4 t = make_float4(0.f, 0.f, 0.f, 0.f);
        if (lane < 48) {
            float4 c4 = *(const float4*)&Cf[r * CFP + lane * 4];
            t.x = c4.x + xr[i].x; t.y = c4.y + xr[i].y;
            t.z = c4.z + xr[i].z; t.w = c4.w + xr[i].w;
        }
        float mean = wave_sum64(t.x + t.y + t.z + t.w) * (1.f / 192.f);
        float ss   = wave_sum64(t.x*t.x + t.y*t.y + t.z*t.z + t.w*t.w) * (1.f / 192.f);
        float inv = rsqrtf(ss - mean * mean + 1e-5f);
        if (lane < 48 && f < n) {
            s16x4 o;
            o[0] = (short)f2bf((t.x - mean) * inv * gv.x + bv.x);
            o[1] = (short)f2bf((t.y - mean) * inv * gv.y + bv.y);
            o[2] = (short)f2bf((t.z - mean) * inv * gv.z + bv.z);
            o[3] = (short)f2bf((t.w - mean) * inv * gv.w + bv.w);
            *(s16x4*)(x1 + (size_t)vv[i] * D_MODEL + lane * 4) = o;
        }
    }
}

// ---------------------------------------------------------------------------
// FFN fused, 1024 threads (round-19/20 winner, Hc stride 208 restored:
// r21's 232 pad broke ds_read_b128 16B alignment -> -12us; 208 reads are
// 2-way aliased which is free on CDNA4).
// ---------------------------------------------------------------------------
__global__ __launch_bounds__(1024)
void ffn_fused(const short* __restrict__ x1, const short* __restrict__ W1,
               const float* __restrict__ b1, const short* __restrict__ W2,
               const float* __restrict__ b2, const float* __restrict__ xin,
               const float* __restrict__ g2, const float* __restrict__ be2,
               const float* __restrict__ gn, const float* __restrict__ bn,
               float* __restrict__ outp, int n)
{
    extern __shared__ char pool[];
    char* Ax  = pool;
    char* W1c = pool + 49152;
    char* W2c = pool + 86016;
    char* Hc  = pool + 125952;
    float* Cf = (float*)(pool + 49152);
    const int rowBase = blockIdx.x * 128;
    const int tid = threadIdx.x;
    const int wid = tid >> 6, lane = tid & 63;
    const int lr = lane & 15, kb = lane >> 4;
    const int wm = wid & 7;
    const int wn = wid >> 3;

    s16x8 w1r[3], w2r[3];
    #pragma unroll
    for (int i = 0; i < 3; ++i) {
        int t = i * 1024 + tid;
        w1r[i] = (s16x8){}; w2r[i] = (s16x8){};
        if (t < 2304) {
            int row = t / 24, c8 = t % 24;
            w1r[i] = *(const s16x8*)(W1 + (size_t)row * 192 + c8 * 8);
            int row2 = t / 12, c82 = t % 12;
            w2r[i] = *(const s16x8*)(W2 + (size_t)row2 * 384 + c82 * 8);
        }
    }

    #pragma unroll
    for (int t = tid; t < 3072; t += 1024) {
        int row = t / 24, c8 = t % 24;
        int grow = rowBase + row;
        s16x8 v = {};
        if (grow < n) v = *(const s16x8*)(x1 + (size_t)grow * 192 + c8 * 8);
        *(s16x8*)(Ax + row * 384 + ((c8 * 16) ^ ((row & 7) << 4))) = v;
    }

    f32x4 acc2[6] = {};
    for (int c = 0; c < 4; ++c) {
        __syncthreads();
        #pragma unroll
        for (int i = 0; i < 3; ++i) {
            int t = i * 1024 + tid;
            if (t < 2304) {
                int row = t / 24, c8 = t % 24;
                *(s16x8*)(W1c + row * 384 + ((c8 * 16) ^ ((row & 7) << 4))) = w1r[i];
                int row2 = t / 12, c82 = t % 12;
                *(s16x8*)(W2c + row2 * 208 + c82 * 16) = w2r[i];
            }
        }
        __syncthreads();
        if (c < 3) {
            #pragma unroll
            for (int i = 0; i < 3; ++i) {
                int t = i * 1024 + tid;
                if (t < 2304) {
                    int row = t / 24, c8 = t % 24;
                    w1r[i] = *(const s16x8*)(W1 + (size_t)((c + 1) * 96 + row) * 192 + c8 * 8);
                    int row2 = t / 12, c82 = t % 12;
                    w2r[i] = *(const s16x8*)(W2 + (size_t)row2 * 384 + (c + 1) * 96 + c82 * 8);
                }
            }
        }
        f32x4 acc1[3] = {};
        #pragma unroll
        for (int ks = 0; ks < 6; ++ks) {
            int row = wm * 16 + lr;
            s16x8 a = *(const s16x8*)(Ax + row * 384 + ((ks * 64 + kb * 16) ^ ((row & 7) << 4)));
            s16x8 b[3];
            #pragma unroll
            for (int fj = 0; fj < 3; ++fj) {
                int brow = wn * 48 + fj * 16 + lr;
                b[fj] = *(const s16x8*)(W1c + brow * 384 + ((ks * 64 + kb * 16) ^ ((brow & 7) << 4)));
            }
            #pragma unroll
            for (int fj = 0; fj < 3; ++fj)
                acc1[fj] = __builtin_amdgcn_mfma_f32_16x16x32_bf16(a, b[fj], acc1[fj], 0, 0, 0);
        }
        #pragma unroll
        for (int fj = 0; fj < 3; ++fj) {
            int col = wn * 48 + fj * 16 + lr;
            float b1v = b1[c * 96 + col];
            #pragma unroll
            for (int r = 0; r < 4; ++r) {
                int row = wm * 16 + kb * 4 + r;
                *(short*)(Hc + row * 208 + col * 2) =
                    (short)f2bf(fmaxf(acc1[fj][r] + b1v, 0.f));
            }
        }
        __syncthreads();
        #pragma unroll
        for (int ks = 0; ks < 3; ++ks) {
            int row = wm * 16 + lr;
            s16x8 a = *(const s16x8*)(Hc + row * 208 + ks * 64 + kb * 16);
            s16x8 b[6];
            #pragma unroll
            for (int fj = 0; fj < 6; ++fj) {
                int brow = wn * 96 + fj * 16 + lr;
                b[fj] = *(const s16x8*)(W2c + brow * 208 + ks * 64 + kb * 16);
            }
            #pragma unroll
            for (int fj = 0; fj < 6; ++fj)
                acc2[fj] = __builtin_amdgcn_mfma_f32_16x16x32_bf16(a, b[fj], acc2[fj], 0, 0, 0);
        }
    }

    float4 xr[8];
    #pragma unroll
    for (int i = 0; i < 8; ++i) {
        int gvx = rowBase + wid * 8 + i;
        xr[i] = (lane < 48 && gvx < n)
              ? *(const float4*)(xin + (size_t)gvx * D_MODEL + lane * 4)
              : make_float4(0.f, 0.f, 0.f, 0.f);
    }
    float4 g2v = (lane < 48) ? *(const float4*)(g2 + lane * 4) : make_float4(0,0,0,0);
    float4 b2v = (lane < 48) ? *(const float4*)(be2 + lane * 4) : make_float4(0,0,0,0);
    float4 gnv = (lane < 48) ? *(const float4*)(gn + lane * 4) : make_float4(0,0,0,0);
    float4 bnv = (lane < 48) ? *(const float4*)(bn + lane * 4) : make_float4(0,0,0,0);

    __syncthreads();
    #pragma unroll
    for (int fj = 0; fj < 6; ++fj) {
        int col = wn * 96 + fj * 16 + lr;
        float bvv = b2[col];
        #pragma unroll
        for (int r = 0; r < 4; ++r) {
            int row = wm * 16 + kb * 4 + r;
            Cf[row * CFP + col] = acc2[fj][r] + bvv;
        }
    }
    __syncthreads();

    #pragma unroll
    for (int i = 0; i < 8; ++i) {
        int r = wid * 8 + i;
        int gvx = rowBase + r;
        float4 t = make_float4(0.f, 0.f, 0.f, 0.f);
        if (lane < 48) {
            float4 f4 = *(const float4*)&Cf[r * CFP + lane * 4];
            int byteoff = r * 384 + (((lane >> 1) << 4) ^ ((r & 7) << 4)) + ((lane & 1) << 3);
            s16x4 xv = *(const s16x4*)(Ax + byteoff);
            t.x = f4.x + bf2f((unsigned short)xv[0]);
            t.y = f4.y + bf2f((unsigned short)xv[1]);
            t.z = f4.z + bf2f((unsigned short)xv[2]);
            t.w = f4.w + bf2f((unsigned short)xv[3]);
        }
        float m1 = wave_sum64(t.x + t.y + t.z + t.w) * (1.f / 192.f);
        float s1 = wave_sum64(t.x*t.x + t.y*t.y + t.z*t.z + t.w*t.w) * (1.f / 192.f);
        float i1 = rsqrtf(s1 - m1 * m1 + 1e-5f);
        float4 t2 = make_float4(0.f, 0.f, 0.f, 0.f);
        if (lane < 48) {
            t2.x = (t.x - m1) * i1 * g2v.x + b2v.x + xr[i].x;
            t2.y = (t.y - m1) * i1 * g2v.y + b2v.y + xr[i].y;
            t2.z = (t.z - m1) * i1 * g2v.z + b2v.z + xr[i].z;
            t2.w = (t.w - m1) * i1 * g2v.w + b2v.w + xr[i].w;
        }
        float m2 = wave_sum64(t2.x + t2.y + t2.z + t2.w) * (1.f / 192.f);
        float s2 = wave_sum64(t2.x*t2.x + t2.y*t2.y + t2.z*t2.z + t2.w*t2.w) * (1.f / 192.f);
        float i2 = rsqrtf(s2 - m2 * m2 + 1e-5f);
        if (lane < 48 && gvx < n) {
            float4 o;
            o.x = (t2.x - m2) * i2 * gnv.x + bnv.x;
            o.y = (t2.y - m2) * i2 * gnv.y + bnv.y;
            o.z = (t2.z - m2) * i2 * gnv.z + bnv.z;
            o.w = (t2.w - m2) * i2 * gnv.w + bnv.w;
            *(float4*)(outp + (size_t)gvx * D_MODEL + lane * 4) = o;
        }
    }
}

// ---------------------------------------------------------------------------
extern "C" void kernel_launch(void* const* d_in, const int* in_sizes, int n_in,
                              void* d_out, int out_size, void* d_ws, size_t ws_size,
                              hipStream_t stream)
{
    (void)in_sizes; (void)n_in; (void)out_size;
    const int N = NVOX;
    const float* src = (const float*)d_in[0];
    const int* inds[2] = {(const int*)d_in[1], (const int*)d_in[2]};
    const unsigned char* mask[2] = {(const unsigned char*)d_in[3], (const unsigned char*)d_in[4]};
    const float* pos[2] = {(const float*)d_in[5], (const float*)d_in[6]};
    const float* Wqkv = (const float*)d_in[7];
    const float* bqkv = (const float*)d_in[8];
    const float* Wo   = (const float*)d_in[9];
    const float* bo   = (const float*)d_in[10];
    const float* W1   = (const float*)d_in[11];
    const float* b1   = (const float*)d_in[12];
    const float* W2   = (const float*)d_in[13];
    const float* b2   = (const float*)d_in[14];
    const float* g1   = (const float*)d_in[15];
    const float* be1  = (const float*)d_in[16];
    const float* g2   = (const float*)d_in[17];
    const float* be2  = (const float*)d_in[18];
    const float* gn   = (const float*)d_in[19];
    const float* bn   = (const float*)d_in[20];

    float* out = (float*)d_out;
    short* wsS = (short*)d_ws;

    const size_t NE = (size_t)N * D_MODEL;
    short* wqkv_b = wsS;
    short* wo_b   = wsS + 221184;
    short* w1_b   = wsS + 294912;
    short* w2_b   = wsS + 442368;
    const size_t base = 1048576;
    short* qk    = wsS + base;
    short* sf    = qk + NE;
    short* qkvb  = sf + NE;
    short* attnb = qkvb + 3 * NE;
    short* x1    = attnb + NE;

    if (ws_size < (base + 7 * NE) * sizeof(short)) return;

    const dim3 blk(256);
    convert_f32_bf16<<<dim3(864), blk, 0, stream>>>(Wqkv, wqkv_b, 221184);
    convert_f32_bf16<<<dim3(288), blk, 0, stream>>>(Wo,   wo_b,   73728);
    convert_f32_bf16<<<dim3(576), blk, 0, stream>>>(W1,   w1_b,   147456);
    convert_f32_bf16<<<dim3(576), blk, 0, stream>>>(W2,   w2_b,   147456);

    const int RT = (N + 127) / 128;                  // 768 row tiles
    for (int i = 0; i < 2; ++i) {
        const float* xin = (i == 0) ? src : out;
        gather_kernel<<<dim3(24570), blk, 0, stream>>>(xin, pos[i], inds[i], qk, sf);
        qkv_direct<<<dim3(6, RT), dim3(512), 0, stream>>>(
            qk, sf, wqkv_b + (size_t)i * 110592, bqkv + i * 576, qkvb, N);
        attn_mfma<<<dim3(S_SETS * N_HEADS / 4), dim3(256), 0, stream>>>(qkvb, mask[i], attnb);
        wo_ln1<<<dim3(RT), dim3(1024), 122880, stream>>>(
            attnb, wo_b + (size_t)i * 36864, bo + i * 192, inds[i], xin,
            g1 + i * 192, be1 + i * 192, x1, N);
        ffn_fused<<<dim3(RT), dim3(1024), 152576, stream>>>(
            x1, w1_b + (size_t)i * 73728, b1 + i * 384, w2_b + (size_t)i * 73728,
            b2 + i * 192, xin, g2 + i * 192, be2 + i * 192,
            gn + i * 192, bn + i * 192, out, N);
    }
}